// Round 1
// baseline (597.274 us; speedup 1.0000x reference)
//
#include <hip/hip_runtime.h>
#include <hip/hip_bf16.h>
#include <math.h>

typedef unsigned int u32;
typedef unsigned long long u64;
typedef unsigned short u16;
typedef __bf16 bf16x8 __attribute__((ext_vector_type(8)));
typedef float f32x4 __attribute__((ext_vector_type(4)));

#define DEV __device__ __forceinline__

DEV u32 bfr(float f){ u32 u = __float_as_uint(f); return (u + 0x7fffu + ((u>>16)&1u)) >> 16; }
DEV float bfl(u32 w){ return __uint_as_float(w << 16); }
DEV float bfh(u32 w){ return __uint_as_float(w & 0xffff0000u); }
DEV float red32(float v){
  v += __shfl_xor(v,1); v += __shfl_xor(v,2); v += __shfl_xor(v,4);
  v += __shfl_xor(v,8); v += __shfl_xor(v,16); return v;
}

// ---------------- init: slots = mu + exp(ls)*noise ----------------
__global__ void kInitSlots(const float* __restrict__ noise, const float* __restrict__ mu,
                           const float* __restrict__ ls, float* __restrict__ slots){
  int i4 = blockIdx.x*256 + threadIdx.x;   // float4 idx, 0..16383
  int d4 = i4 & 31;
  float4 nv = ((const float4*)noise)[i4];
  float4 mv = ((const float4*)mu)[d4];
  float4 lv = ((const float4*)ls)[d4];
  float4 r;
  r.x = mv.x + expf(lv.x)*nv.x;
  r.y = mv.y + expf(lv.y)*nv.y;
  r.z = mv.z + expf(lv.z)*nv.z;
  r.w = mv.w + expf(lv.w)*nv.w;
  ((float4*)slots)[i4] = r;
}

// ---------------- init: Wg = [Wk;Wv]*g (bf16), c1 = sum g*W, c2 = sum b*W ----------------
__global__ void kInitW(const float* __restrict__ Wk, const float* __restrict__ Wv,
                       const float* __restrict__ g, const float* __restrict__ bb,
                       u16* __restrict__ wg, float* __restrict__ c1, float* __restrict__ c2){
  int e = threadIdx.x;  // 0..255
  const float4* src = (const float4*)((e < 128) ? (Wk + e*128) : (Wv + (e-128)*128));
  float a1 = 0.f, a2 = 0.f;
  #pragma unroll
  for (int d4 = 0; d4 < 32; ++d4){
    float4 wv = src[d4];
    float4 gv = ((const float4*)g)[d4];
    float4 bv = ((const float4*)bb)[d4];
    a1 += wv.x*gv.x + wv.y*gv.y + wv.z*gv.z + wv.w*gv.w;
    a2 += wv.x*bv.x + wv.y*bv.y + wv.z*bv.z + wv.w*bv.w;
    u32 w0 = bfr(wv.x*gv.x) | (bfr(wv.y*gv.y) << 16);
    u32 w1 = bfr(wv.z*gv.z) | (bfr(wv.w*gv.w) << 16);
    *(uint2*)&wg[e*128 + d4*4] = make_uint2(w0, w1);
  }
  c1[e] = a1; c2[e] = a2;
}

// ---------------- kernel A: fused-LN K/V projection via bf16 MFMA ----------------
// k_e = rstd*(dot(x, Wg_e) - mean*c1_e) + c2_e ; same for v (cols 128..255)
__global__ __launch_bounds__(512, 2) void kA(const float* __restrict__ x,
    const u16* __restrict__ wg, const float* __restrict__ c1g, const float* __restrict__ c2g,
    u16* __restrict__ kbuf, u16* __restrict__ vbuf)
{
  __shared__ __align__(16) u16 sWg[256*128];
  __shared__ __align__(16) u16 sXn[256*128];
  __shared__ float sM[256], sR[256], sC1[256], sC2[256];
  const int t = threadIdx.x, l = t & 63, w = t >> 6;

  // stage Wg (swizzled 16B granules: g' = g ^ (row&7))
  const uint4* wg4 = (const uint4*)wg;
  #pragma unroll
  for (int p = 0; p < 8; ++p){
    int G = t + p*512;           // granule idx
    int row = G >> 4, g = G & 15;
    uint4 v = wg4[G];
    *(uint4*)&sWg[row*128 + ((g ^ (row & 7)) << 3)] = v;
  }
  if (t < 256){ sC1[t] = c1g[t]; sC2[t] = c2g[t]; }
  __syncthreads();

  const float4* x4 = (const float4*)x;
  #pragma unroll 1
  for (int it = 0; it < 4; ++it){
    const int R0 = blockIdx.x*1024 + it*256 + w*32;   // wave's 32-row base
    float4 X[16];
    #pragma unroll
    for (int i = 0; i < 16; ++i) X[i] = x4[(size_t)R0*32 + i*64 + l];
    #pragma unroll
    for (int i = 0; i < 16; ++i){
      float s  = X[i].x + X[i].y + X[i].z + X[i].w;
      float ss = X[i].x*X[i].x + X[i].y*X[i].y + X[i].z*X[i].z + X[i].w*X[i].w;
      s = red32(s); ss = red32(ss);
      float m = s * 0.0078125f;
      float var = ss * 0.0078125f - m*m;
      float rstd = rsqrtf(var + 1e-5f);
      int rl = i*2 + (l >> 5);
      int rowfull = w*32 + rl;
      if ((l & 31) == 0){ sM[rowfull] = m; sR[rowfull] = rstd; }
      u32 w0 = bfr(X[i].x) | (bfr(X[i].y) << 16);
      u32 w1 = bfr(X[i].z) | (bfr(X[i].w) << 16);
      int us = rowfull*128 + (((l & 31)*4) ^ ((rl & 7) << 3));
      *(uint2*)&sXn[us] = make_uint2(w0, w1);
    }
    // A fragments: row = base + (l&15), k-granule g = kt*4 + (l>>4)
    uint4 af[2][4];
    #pragma unroll
    for (int rs_ = 0; rs_ < 2; ++rs_)
      #pragma unroll
      for (int kt = 0; kt < 4; ++kt){
        int row = w*32 + rs_*16 + (l & 15);
        int g = kt*4 + (l >> 4);
        af[rs_][kt] = *(const uint4*)&sXn[row*128 + ((g ^ (row & 7)) << 3)];
      }
    f32x4 acc[2][16];
    #pragma unroll
    for (int a_ = 0; a_ < 2; ++a_)
      #pragma unroll
      for (int c_ = 0; c_ < 16; ++c_) acc[a_][c_] = (f32x4){0.f,0.f,0.f,0.f};
    #pragma unroll
    for (int ct = 0; ct < 16; ++ct){
      uint4 bf[4];
      #pragma unroll
      for (int kt = 0; kt < 4; ++kt){
        int wr = ct*16 + (l & 15);
        int g = kt*4 + (l >> 4);
        bf[kt] = *(const uint4*)&sWg[wr*128 + ((g ^ (wr & 7)) << 3)];
      }
      #pragma unroll
      for (int rs_ = 0; rs_ < 2; ++rs_)
        #pragma unroll
        for (int kt = 0; kt < 4; ++kt)
          acc[rs_][ct] = __builtin_amdgcn_mfma_f32_16x16x32_bf16(
              __builtin_bit_cast(bf16x8, af[rs_][kt]),
              __builtin_bit_cast(bf16x8, bf[kt]),
              acc[rs_][ct], 0, 0, 0);
    }
    // epilogue: per-row affine + bf16 store
    #pragma unroll
    for (int rs_ = 0; rs_ < 2; ++rs_){
      float mv[4], rv[4];
      #pragma unroll
      for (int r = 0; r < 4; ++r){
        int row = w*32 + rs_*16 + (l >> 4)*4 + r;
        mv[r] = sM[row]; rv[r] = sR[row];
      }
      #pragma unroll
      for (int ct = 0; ct < 16; ++ct){
        int colb = ct*16 + (l & 15);
        float c1v = sC1[colb], c2v = sC2[colb];
        #pragma unroll
        for (int r = 0; r < 4; ++r){
          float valf = rv[r]*(acc[rs_][ct][r] - mv[r]*c1v) + c2v;
          u16 hv = (u16)bfr(valf);
          size_t rowg = (size_t)R0 + rs_*16 + (l >> 4)*4 + r;
          if (colb < 128) kbuf[rowg*128 + colb] = hv;
          else            vbuf[rowg*128 + (colb - 128)] = hv;
        }
      }
    }
  }
}

// ---------------- kernel B: q = LN(slots)@Wq^T*scale; stream k,v; partial upd/rowsum ----------------
__global__ __launch_bounds__(256) void kB(const float* __restrict__ slots,
   const u16* __restrict__ kbuf, const u16* __restrict__ vbuf,
   const float* __restrict__ Wq, const float* __restrict__ lng, const float* __restrict__ lnb,
   float* __restrict__ part, float* __restrict__ attn_out, int write_attn)
{
  const int t = threadIdx.x;
  const int b = blockIdx.x >> 3, chunk = blockIdx.x & 7;
  const int wid = t >> 6, lane = t & 63;
  const int k8 = t >> 5, q32 = t & 31;
  __shared__ __align__(16) float sSn[8*128];
  __shared__ __align__(16) float sQ[8*128];
  __shared__ __align__(16) u64 sKT[32*64];
  __shared__ __align__(16) u16 sV[64*136];
  __shared__ float sDots[8*64];
  __shared__ float sAttn[8*64];

  // s_n = LN(slots[b]) with ln_sl
  {
    float4 sv = ((const float4*)slots)[b*256 + t];
    float s  = sv.x + sv.y + sv.z + sv.w;
    float ss = sv.x*sv.x + sv.y*sv.y + sv.z*sv.z + sv.w*sv.w;
    s = red32(s); ss = red32(ss);
    float m = s*0.0078125f, var = ss*0.0078125f - m*m;
    float rstd = rsqrtf(var + 1e-5f);
    float4 gv = ((const float4*)lng)[q32], bv = ((const float4*)lnb)[q32];
    float4 sn;
    sn.x = (sv.x - m)*rstd*gv.x + bv.x;
    sn.y = (sv.y - m)*rstd*gv.y + bv.y;
    sn.z = (sv.z - m)*rstd*gv.z + bv.z;
    sn.w = (sv.w - m)*rstd*gv.w + bv.w;
    *(float4*)&sSn[t*4] = sn;
  }
  __syncthreads();
  // q[k][e] (scale folded in)
  {
    const float4* Wq4 = (const float4*)Wq;
    #pragma unroll
    for (int i = 0; i < 4; ++i){
      int e = i*32 + q32;
      float acc = 0.f;
      #pragma unroll
      for (int d4 = 0; d4 < 32; ++d4){
        float4 qs = *(const float4*)&sSn[k8*128 + d4*4];
        float4 wv = Wq4[e*32 + d4];
        acc = fmaf(qs.x,wv.x,acc); acc = fmaf(qs.y,wv.y,acc);
        acc = fmaf(qs.z,wv.z,acc); acc = fmaf(qs.w,wv.w,acc);
      }
      sQ[k8*128 + e] = acc * 0.08838834764831845f;
    }
  }
  __syncthreads();

  float ua0=0.f, ua1=0.f, ua2=0.f, ua3=0.f;
  float rsacc[8] = {0,0,0,0,0,0,0,0};
  const int dk0 = wid*2, dk1 = wid*2 + 1;

  for (int tile = 0; tile < 8; ++tile){
    const int n0 = chunk*512 + tile*64;
    const uint4* kg = (const uint4*)(kbuf + (size_t)(b*4096 + n0)*128);
    const uint4* vg = (const uint4*)(vbuf + (size_t)(b*4096 + n0)*128);
    #pragma unroll
    for (int p = 0; p < 4; ++p){
      int fl = t + p*256;
      int nl = fl >> 4, gb = fl & 15;
      uint4 kvv = kg[fl];
      int g0 = gb*2;
      sKT[g0*64 + (nl ^ (g0 & 15))]         = ((u64)kvv.y << 32) | (u64)kvv.x;
      sKT[(g0+1)*64 + (nl ^ ((g0+1) & 15))] = ((u64)kvv.w << 32) | (u64)kvv.z;
      uint4 vvv = vg[fl];
      *(uint4*)&sV[nl*136 + gb*8] = vvv;
    }
    __syncthreads();
    // dots: wave w -> slots 2w, 2w+1; lane = n
    {
      float a0 = 0.f, a1 = 0.f;
      #pragma unroll
      for (int g = 0; g < 32; ++g){
        u64 kk = sKT[g*64 + (lane ^ (g & 15))];
        u32 w0 = (u32)kk, w1 = (u32)(kk >> 32);
        float f0 = bfl(w0), f1 = bfh(w0), f2 = bfl(w1), f3 = bfh(w1);
        float4 q0 = *(const float4*)&sQ[dk0*128 + g*4];
        float4 q1 = *(const float4*)&sQ[dk1*128 + g*4];
        a0 = fmaf(f0,q0.x,a0); a0 = fmaf(f1,q0.y,a0); a0 = fmaf(f2,q0.z,a0); a0 = fmaf(f3,q0.w,a0);
        a1 = fmaf(f0,q1.x,a1); a1 = fmaf(f1,q1.y,a1); a1 = fmaf(f2,q1.z,a1); a1 = fmaf(f3,q1.w,a1);
      }
      sDots[dk0*64 + lane] = a0;
      sDots[dk1*64 + lane] = a1;
    }
    __syncthreads();
    if (t < 64){
      float dv[8], ev[8];
      #pragma unroll
      for (int j = 0; j < 8; ++j) dv[j] = sDots[j*64 + t];
      float mx = dv[0];
      #pragma unroll
      for (int j = 1; j < 8; ++j) mx = fmaxf(mx, dv[j]);
      float sum = 0.f;
      #pragma unroll
      for (int j = 0; j < 8; ++j){ ev[j] = expf(dv[j] - mx); sum += ev[j]; }
      float inv = 1.f/sum;
      #pragma unroll
      for (int j = 0; j < 8; ++j){
        float aa = ev[j]*inv;
        sAttn[j*64 + t] = aa;
        rsacc[j] += aa;
        if (write_attn) attn_out[(size_t)(b*8 + j)*4096 + n0 + t] = aa;
      }
    }
    __syncthreads();
    // updates: thread (k8, q32*4)
    #pragma unroll 8
    for (int n = 0; n < 64; ++n){
      float a = sAttn[k8*64 + n];
      u64 vv = *(const u64*)&sV[n*136 + q32*4];
      u32 w0 = (u32)vv, w1 = (u32)(vv >> 32);
      ua0 = fmaf(a, bfl(w0), ua0);
      ua1 = fmaf(a, bfh(w0), ua1);
      ua2 = fmaf(a, bfl(w1), ua2);
      ua3 = fmaf(a, bfh(w1), ua3);
    }
    __syncthreads();
  }
  float* pb = part + (size_t)(b*8 + chunk)*1040;
  *(float4*)&pb[t*4] = make_float4(ua0, ua1, ua2, ua3);
  if (wid == 0){
    #pragma unroll
    for (int j = 0; j < 8; ++j){
      float v = rsacc[j];
      v += __shfl_xor(v,1); v += __shfl_xor(v,2); v += __shfl_xor(v,4);
      v += __shfl_xor(v,8); v += __shfl_xor(v,16); v += __shfl_xor(v,32);
      if (lane == 0) pb[1024 + j] = v;
    }
  }
}

// ---------------- kernel C: reduce partials -> updates -> GRU -> MLP -> new slots ----------------
DEV void stage128(float* sW, const float* src, int t){
  const float4* s4 = (const float4*)src;
  #pragma unroll
  for (int p = 0; p < 4; ++p){
    int fl = t + p*256;          // float4 idx 0..1023 (32 rows x 32 granules)
    int row = fl >> 5, gq = fl & 31;
    *(float4*)&sW[row*128 + ((gq ^ (row & 31)) << 2)] = s4[fl];
  }
}
DEV float dot128sw(const float* sW, int row, const float* vec){
  float acc = 0.f;
  #pragma unroll
  for (int d4 = 0; d4 < 32; ++d4){
    float4 wv = *(const float4*)&sW[row*128 + ((d4 ^ (row & 31)) << 2)];
    float4 uv = *(const float4*)&vec[d4*4];
    acc = fmaf(wv.x,uv.x,acc); acc = fmaf(wv.y,uv.y,acc);
    acc = fmaf(wv.z,uv.z,acc); acc = fmaf(wv.w,uv.w,acc);
  }
  return acc;
}

__global__ __launch_bounds__(256) void kC(const float* __restrict__ part,
  float* __restrict__ slots, const float* __restrict__ Wih, const float* __restrict__ Whh,
  const float* __restrict__ bih, const float* __restrict__ bhh,
  const float* __restrict__ lng, const float* __restrict__ lnb,
  const float* __restrict__ W1, const float* __restrict__ b1,
  const float* __restrict__ W2, const float* __restrict__ b2,
  float* __restrict__ out_slots, int last)
{
  const int t = threadIdx.x, b = blockIdx.x;
  const int k8 = t >> 5, q32 = t & 31;
  __shared__ __align__(16) float sUp[1024], sSp[1024], sSl[1024], sH[1024];
  __shared__ __align__(16) float sGxn[1024], sGhn[1024];
  __shared__ __align__(16) float sGs[2048], sH1[2048];
  __shared__ __align__(16) float sW[4224];
  __shared__ float sRs[8];

  if (t < 8){
    float s = 1e-8f;
    #pragma unroll
    for (int c = 0; c < 8; ++c) s += part[(size_t)(b*8 + c)*1040 + 1024 + t];
    sRs[t] = s;
  }
  __syncthreads();
  {
    float4 u = {0,0,0,0};
    #pragma unroll
    for (int c = 0; c < 8; ++c){
      float4 pv = *(const float4*)&part[(size_t)(b*8 + c)*1040 + t*4];
      u.x += pv.x; u.y += pv.y; u.z += pv.z; u.w += pv.w;
    }
    float inv = 1.f/sRs[k8];
    u.x *= inv; u.y *= inv; u.z *= inv; u.w *= inv;
    *(float4*)&sUp[t*4] = u;
    *(float4*)&sSp[t*4] = ((const float4*)slots)[b*256 + t];
  }
  __syncthreads();
  // GRU gates (chunks of 32 rows of Wih/Whh)
  for (int ch = 0; ch < 12; ++ch){
    stage128(sW, Wih + ch*32*128, t);
    __syncthreads();
    int gg = ch*32 + q32;
    float acc = dot128sw(sW, q32, sUp + k8*128) + bih[gg];
    if (gg < 256) sGs[k8*256 + gg] = acc; else sGxn[k8*128 + gg - 256] = acc;
    __syncthreads();
    stage128(sW, Whh + ch*32*128, t);
    __syncthreads();
    float acc2 = dot128sw(sW, q32, sSp + k8*128) + bhh[gg];
    if (gg < 256) sGs[k8*256 + gg] += acc2; else sGhn[k8*128 + gg - 256] = acc2;
    __syncthreads();
  }
  // combine gates
  #pragma unroll
  for (int p = 0; p < 4; ++p){
    int idx = t + p*256;
    int k = idx >> 7, j = idx & 127;
    float r = 1.f/(1.f + expf(-sGs[k*256 + j]));
    float z = 1.f/(1.f + expf(-sGs[k*256 + 128 + j]));
    float nn = tanhf(sGxn[k*128 + j] + r*sGhn[k*128 + j]);
    sSl[k*128 + j] = (1.f - z)*nn + z*sSp[k*128 + j];
  }
  __syncthreads();
  // LN (ln_mlp)
  {
    float4 xv = *(const float4*)&sSl[t*4];
    float s  = xv.x + xv.y + xv.z + xv.w;
    float ss = xv.x*xv.x + xv.y*xv.y + xv.z*xv.z + xv.w*xv.w;
    s = red32(s); ss = red32(ss);
    float m = s*0.0078125f, var = ss*0.0078125f - m*m;
    float rstd = rsqrtf(var + 1e-5f);
    float4 gv = ((const float4*)lng)[q32], bv = ((const float4*)lnb)[q32];
    float4 h;
    h.x = (xv.x - m)*rstd*gv.x + bv.x;
    h.y = (xv.y - m)*rstd*gv.y + bv.y;
    h.z = (xv.z - m)*rstd*gv.z + bv.z;
    h.w = (xv.w - m)*rstd*gv.w + bv.w;
    *(float4*)&sH[t*4] = h;
  }
  __syncthreads();
  // MLP layer 1 + exact GELU
  for (int ch = 0; ch < 8; ++ch){
    stage128(sW, W1 + ch*32*128, t);
    __syncthreads();
    int hc = ch*32 + q32;
    float acc = dot128sw(sW, q32, sH + k8*128) + b1[hc];
    sH1[k8*256 + hc] = 0.5f*acc*(1.f + erff(acc*0.70710678118654752f));
    __syncthreads();
  }
  // MLP layer 2 (+residual)
  for (int ch = 0; ch < 8; ++ch){
    {
      const float4* s4 = (const float4*)(W2 + ch*16*256);
      #pragma unroll
      for (int p = 0; p < 4; ++p){
        int fl = t + p*256;       // 16 rows x 64 granules
        int row = fl >> 6, c4 = fl & 63;
        *(float4*)&sW[row*260 + c4*4] = s4[fl];
      }
    }
    __syncthreads();
    int to = t >> 1, half = t & 1;
    int rloc = to & 15, k2 = to >> 4;
    int d_ = ch*16 + rloc;
    float acc = 0.f;
    #pragma unroll
    for (int d4 = 0; d4 < 32; ++d4){
      float4 wv = *(const float4*)&sW[rloc*260 + half*128 + d4*4];
      float4 hv = *(const float4*)&sH1[k2*256 + half*128 + d4*4];
      acc = fmaf(wv.x,hv.x,acc); acc = fmaf(wv.y,hv.y,acc);
      acc = fmaf(wv.z,hv.z,acc); acc = fmaf(wv.w,hv.w,acc);
    }
    acc += __shfl_xor(acc, 1);
    if (half == 0) sSl[k2*128 + d_] = sSl[k2*128 + d_] + acc + b2[d_];
    __syncthreads();
  }
  // write back
  {
    float4 res = *(const float4*)&sSl[t*4];
    ((float4*)slots)[b*256 + t] = res;
    if (last) ((float4*)out_slots)[b*256 + t] = res;
  }
}

extern "C" void kernel_launch(void* const* d_in, const int* in_sizes, int n_in,
                              void* d_out, int out_size, void* d_ws, size_t ws_size,
                              hipStream_t stream)
{
  const float* inputs   = (const float*)d_in[0];
  const float* noise    = (const float*)d_in[1];
  const float* ln_in_g  = (const float*)d_in[2];
  const float* ln_in_b  = (const float*)d_in[3];
  const float* ln_sl_g  = (const float*)d_in[4];
  const float* ln_sl_b  = (const float*)d_in[5];
  const float* ln_mlp_g = (const float*)d_in[6];
  const float* ln_mlp_b = (const float*)d_in[7];
  const float* slots_mu = (const float*)d_in[8];
  const float* slots_ls = (const float*)d_in[9];
  const float* Wq  = (const float*)d_in[10];
  const float* Wk  = (const float*)d_in[11];
  const float* Wv  = (const float*)d_in[12];
  const float* Wih = (const float*)d_in[13];
  const float* Whh = (const float*)d_in[14];
  const float* bih = (const float*)d_in[15];
  const float* bhh = (const float*)d_in[16];
  const float* W1  = (const float*)d_in[17];
  const float* b1  = (const float*)d_in[18];
  const float* W2  = (const float*)d_in[19];
  const float* b2  = (const float*)d_in[20];
  float* out = (float*)d_out;

  char* ws = (char*)d_ws;
  u16*   kbuf  = (u16*)ws;                       // 67,108,864 B
  u16*   vbuf  = (u16*)(ws + 67108864);          // 67,108,864 B
  float* slots = (float*)(ws + 134217728);       // 262,144 B
  u16*   wg    = (u16*)(ws + 134479872);         // 65,536 B
  float* c1    = (float*)(ws + 134545408);       // 1,024 B
  float* c2    = (float*)(ws + 134546432);       // 1,024 B
  float* part  = (float*)(ws + 134547456);       // 2,129,920 B

  kInitSlots<<<64, 256, 0, stream>>>(noise, slots_mu, slots_ls, slots);
  kInitW<<<1, 256, 0, stream>>>(Wk, Wv, ln_in_g, ln_in_b, wg, c1, c2);
  kA<<<256, 512, 0, stream>>>(inputs, wg, c1, c2, kbuf, vbuf);
  for (int it = 0; it < 3; ++it){
    kB<<<512, 256, 0, stream>>>(slots, kbuf, vbuf, Wq, ln_sl_g, ln_sl_b,
                                part, out + 65536, it == 2);
    kC<<<64, 256, 0, stream>>>(part, slots, Wih, Whh, bih, bhh,
                               ln_mlp_g, ln_mlp_b, W1, b1, W2, b2, out, it == 2);
  }
}

// Round 2
// 398.793 us; speedup vs baseline: 1.4977x; 1.4977x over previous
//
#include <hip/hip_runtime.h>
#include <hip/hip_bf16.h>
#include <math.h>

typedef unsigned int u32;
typedef unsigned long long u64;
typedef unsigned short u16;
typedef __bf16 bf16x8 __attribute__((ext_vector_type(8)));
typedef float f32x4 __attribute__((ext_vector_type(4)));

#define DEV __device__ __forceinline__

DEV u32 bfr(float f){ u32 u = __float_as_uint(f); return (u + 0x7fffu + ((u>>16)&1u)) >> 16; }
DEV float bfl(u32 w){ return __uint_as_float(w << 16); }
DEV float bfh(u32 w){ return __uint_as_float(w & 0xffff0000u); }
DEV float red32(float v){
  v += __shfl_xor(v,1); v += __shfl_xor(v,2); v += __shfl_xor(v,4);
  v += __shfl_xor(v,8); v += __shfl_xor(v,16); return v;
}

// ---------------- init: slots = mu + exp(ls)*noise ----------------
__global__ void kInitSlots(const float* __restrict__ noise, const float* __restrict__ mu,
                           const float* __restrict__ ls, float* __restrict__ slots){
  int i4 = blockIdx.x*256 + threadIdx.x;   // float4 idx, 0..16383
  int d4 = i4 & 31;
  float4 nv = ((const float4*)noise)[i4];
  float4 mv = ((const float4*)mu)[d4];
  float4 lv = ((const float4*)ls)[d4];
  float4 r;
  r.x = mv.x + expf(lv.x)*nv.x;
  r.y = mv.y + expf(lv.y)*nv.y;
  r.z = mv.z + expf(lv.z)*nv.z;
  r.w = mv.w + expf(lv.w)*nv.w;
  ((float4*)slots)[i4] = r;
}

// ---------------- init: Wg = [Wk;Wv]*g (bf16), c1 = sum g*W, c2 = sum b*W ----------------
__global__ void kInitW(const float* __restrict__ Wk, const float* __restrict__ Wv,
                       const float* __restrict__ g, const float* __restrict__ bb,
                       u16* __restrict__ wg, float* __restrict__ c1, float* __restrict__ c2){
  int e = threadIdx.x;  // 0..255
  const float4* src = (const float4*)((e < 128) ? (Wk + e*128) : (Wv + (e-128)*128));
  float a1 = 0.f, a2 = 0.f;
  #pragma unroll
  for (int d4 = 0; d4 < 32; ++d4){
    float4 wv = src[d4];
    float4 gv = ((const float4*)g)[d4];
    float4 bv = ((const float4*)bb)[d4];
    a1 += wv.x*gv.x + wv.y*gv.y + wv.z*gv.z + wv.w*gv.w;
    a2 += wv.x*bv.x + wv.y*bv.y + wv.z*bv.z + wv.w*bv.w;
    u32 w0 = bfr(wv.x*gv.x) | (bfr(wv.y*gv.y) << 16);
    u32 w1 = bfr(wv.z*gv.z) | (bfr(wv.w*gv.w) << 16);
    *(uint2*)&wg[e*128 + d4*4] = make_uint2(w0, w1);
  }
  c1[e] = a1; c2[e] = a2;
}

// ---------------- init: transposed weight packs for kC ----------------
// gruT[d*384+g] = {Wih[g*128+d], Whh[g*128+d]}  (float2, 393216 B)
// w1T[d*256+h]  = W1[h*128+d]                   (131072 B)
// w2T[j*128+d]  = W2[d*256+j]                   (131072 B)
__global__ void kInitT(const float* __restrict__ Wih, const float* __restrict__ Whh,
                       const float* __restrict__ W1, const float* __restrict__ W2,
                       float2* __restrict__ gruT, float* __restrict__ w1T, float* __restrict__ w2T){
  int i = blockIdx.x*256 + threadIdx.x;
  if (i < 49152){
    int d = i / 384, g = i - d*384;
    gruT[i] = make_float2(Wih[g*128 + d], Whh[g*128 + d]);
  } else if (i < 81920){
    int j = i - 49152;
    int d = j >> 8, h = j & 255;
    w1T[j] = W1[h*128 + d];
  } else if (i < 114688){
    int q = i - 81920;
    int j = q >> 7, d = q & 127;
    w2T[q] = W2[d*256 + j];
  }
}

// ---------------- kernel A: fused-LN K/V projection via bf16 MFMA ----------------
// k_e = rstd*(dot(x, Wg_e) - mean*c1_e) + c2_e ; same for v (cols 128..255)
__global__ __launch_bounds__(512, 2) void kA(const float* __restrict__ x,
    const u16* __restrict__ wg, const float* __restrict__ c1g, const float* __restrict__ c2g,
    u16* __restrict__ kbuf, u16* __restrict__ vbuf)
{
  __shared__ __align__(16) u16 sWg[256*128];
  __shared__ __align__(16) u16 sXn[256*128];
  __shared__ float sM[256], sR[256], sC1[256], sC2[256];
  const int t = threadIdx.x, l = t & 63, w = t >> 6;

  // stage Wg (swizzled 16B granules: g' = g ^ (row&7))
  const uint4* wg4 = (const uint4*)wg;
  #pragma unroll
  for (int p = 0; p < 8; ++p){
    int G = t + p*512;           // granule idx
    int row = G >> 4, g = G & 15;
    uint4 v = wg4[G];
    *(uint4*)&sWg[row*128 + ((g ^ (row & 7)) << 3)] = v;
  }
  if (t < 256){ sC1[t] = c1g[t]; sC2[t] = c2g[t]; }
  __syncthreads();

  const float4* x4 = (const float4*)x;
  #pragma unroll 1
  for (int it = 0; it < 4; ++it){
    const int R0 = blockIdx.x*1024 + it*256 + w*32;   // wave's 32-row base
    float4 X[16];
    #pragma unroll
    for (int i = 0; i < 16; ++i) X[i] = x4[(size_t)R0*32 + i*64 + l];
    #pragma unroll
    for (int i = 0; i < 16; ++i){
      float s  = X[i].x + X[i].y + X[i].z + X[i].w;
      float ss = X[i].x*X[i].x + X[i].y*X[i].y + X[i].z*X[i].z + X[i].w*X[i].w;
      s = red32(s); ss = red32(ss);
      float m = s * 0.0078125f;
      float var = ss * 0.0078125f - m*m;
      float rstd = rsqrtf(var + 1e-5f);
      int rl = i*2 + (l >> 5);
      int rowfull = w*32 + rl;
      if ((l & 31) == 0){ sM[rowfull] = m; sR[rowfull] = rstd; }
      u32 w0 = bfr(X[i].x) | (bfr(X[i].y) << 16);
      u32 w1 = bfr(X[i].z) | (bfr(X[i].w) << 16);
      int us = rowfull*128 + (((l & 31)*4) ^ ((rl & 7) << 3));
      *(uint2*)&sXn[us] = make_uint2(w0, w1);
    }
    // A fragments: row = base + (l&15), k-granule g = kt*4 + (l>>4)
    uint4 af[2][4];
    #pragma unroll
    for (int rs_ = 0; rs_ < 2; ++rs_)
      #pragma unroll
      for (int kt = 0; kt < 4; ++kt){
        int row = w*32 + rs_*16 + (l & 15);
        int g = kt*4 + (l >> 4);
        af[rs_][kt] = *(const uint4*)&sXn[row*128 + ((g ^ (row & 7)) << 3)];
      }
    f32x4 acc[2][16];
    #pragma unroll
    for (int a_ = 0; a_ < 2; ++a_)
      #pragma unroll
      for (int c_ = 0; c_ < 16; ++c_) acc[a_][c_] = (f32x4){0.f,0.f,0.f,0.f};
    #pragma unroll
    for (int ct = 0; ct < 16; ++ct){
      uint4 bf[4];
      #pragma unroll
      for (int kt = 0; kt < 4; ++kt){
        int wr = ct*16 + (l & 15);
        int g = kt*4 + (l >> 4);
        bf[kt] = *(const uint4*)&sWg[wr*128 + ((g ^ (wr & 7)) << 3)];
      }
      #pragma unroll
      for (int rs_ = 0; rs_ < 2; ++rs_)
        #pragma unroll
        for (int kt = 0; kt < 4; ++kt)
          acc[rs_][ct] = __builtin_amdgcn_mfma_f32_16x16x32_bf16(
              __builtin_bit_cast(bf16x8, af[rs_][kt]),
              __builtin_bit_cast(bf16x8, bf[kt]),
              acc[rs_][ct], 0, 0, 0);
    }
    // epilogue: per-row affine + bf16 store
    #pragma unroll
    for (int rs_ = 0; rs_ < 2; ++rs_){
      float mv[4], rv[4];
      #pragma unroll
      for (int r = 0; r < 4; ++r){
        int row = w*32 + rs_*16 + (l >> 4)*4 + r;
        mv[r] = sM[row]; rv[r] = sR[row];
      }
      #pragma unroll
      for (int ct = 0; ct < 16; ++ct){
        int colb = ct*16 + (l & 15);
        float c1v = sC1[colb], c2v = sC2[colb];
        #pragma unroll
        for (int r = 0; r < 4; ++r){
          float valf = rv[r]*(acc[rs_][ct][r] - mv[r]*c1v) + c2v;
          u16 hv = (u16)bfr(valf);
          size_t rowg = (size_t)R0 + rs_*16 + (l >> 4)*4 + r;
          if (colb < 128) kbuf[rowg*128 + colb] = hv;
          else            vbuf[rowg*128 + (colb - 128)] = hv;
        }
      }
    }
  }
}

// ---------------- kernel B: q = LN(slots)@Wq^T*scale; stream k,v; partial upd/rowsum ----------------
__global__ __launch_bounds__(256) void kB(const float* __restrict__ slots,
   const u16* __restrict__ kbuf, const u16* __restrict__ vbuf,
   const float* __restrict__ Wq, const float* __restrict__ lng, const float* __restrict__ lnb,
   float* __restrict__ part, float* __restrict__ attn_out, int write_attn)
{
  const int t = threadIdx.x;
  const int b = blockIdx.x >> 3, chunk = blockIdx.x & 7;
  const int wid = t >> 6, lane = t & 63;
  const int k8 = t >> 5, q32 = t & 31;
  __shared__ __align__(16) float sSn[8*128];
  __shared__ __align__(16) float sQ[8*128];
  __shared__ __align__(16) u64 sKT[32*64];
  __shared__ __align__(16) u16 sV[64*136];
  __shared__ float sDots[8*64];
  __shared__ float sAttn[8*64];

  // s_n = LN(slots[b]) with ln_sl
  {
    float4 sv = ((const float4*)slots)[b*256 + t];
    float s  = sv.x + sv.y + sv.z + sv.w;
    float ss = sv.x*sv.x + sv.y*sv.y + sv.z*sv.z + sv.w*sv.w;
    s = red32(s); ss = red32(ss);
    float m = s*0.0078125f, var = ss*0.0078125f - m*m;
    float rstd = rsqrtf(var + 1e-5f);
    float4 gv = ((const float4*)lng)[q32], bv = ((const float4*)lnb)[q32];
    float4 sn;
    sn.x = (sv.x - m)*rstd*gv.x + bv.x;
    sn.y = (sv.y - m)*rstd*gv.y + bv.y;
    sn.z = (sv.z - m)*rstd*gv.z + bv.z;
    sn.w = (sv.w - m)*rstd*gv.w + bv.w;
    *(float4*)&sSn[t*4] = sn;
  }
  __syncthreads();
  // q[k][e] (scale folded in)
  {
    const float4* Wq4 = (const float4*)Wq;
    #pragma unroll
    for (int i = 0; i < 4; ++i){
      int e = i*32 + q32;
      float acc = 0.f;
      #pragma unroll
      for (int d4 = 0; d4 < 32; ++d4){
        float4 qs = *(const float4*)&sSn[k8*128 + d4*4];
        float4 wv = Wq4[e*32 + d4];
        acc = fmaf(qs.x,wv.x,acc); acc = fmaf(qs.y,wv.y,acc);
        acc = fmaf(qs.z,wv.z,acc); acc = fmaf(qs.w,wv.w,acc);
      }
      sQ[k8*128 + e] = acc * 0.08838834764831845f;
    }
  }
  __syncthreads();

  float ua0=0.f, ua1=0.f, ua2=0.f, ua3=0.f;
  float rsacc[8] = {0,0,0,0,0,0,0,0};
  const int dk0 = wid*2, dk1 = wid*2 + 1;

  for (int tile = 0; tile < 8; ++tile){
    const int n0 = chunk*512 + tile*64;
    const uint4* kg = (const uint4*)(kbuf + (size_t)(b*4096 + n0)*128);
    const uint4* vg = (const uint4*)(vbuf + (size_t)(b*4096 + n0)*128);
    #pragma unroll
    for (int p = 0; p < 4; ++p){
      int fl = t + p*256;
      int nl = fl >> 4, gb = fl & 15;
      uint4 kvv = kg[fl];
      int g0 = gb*2;
      sKT[g0*64 + (nl ^ (g0 & 15))]         = ((u64)kvv.y << 32) | (u64)kvv.x;
      sKT[(g0+1)*64 + (nl ^ ((g0+1) & 15))] = ((u64)kvv.w << 32) | (u64)kvv.z;
      uint4 vvv = vg[fl];
      *(uint4*)&sV[nl*136 + gb*8] = vvv;
    }
    __syncthreads();
    // dots: wave w -> slots 2w, 2w+1; lane = n
    {
      float a0 = 0.f, a1 = 0.f;
      #pragma unroll
      for (int g = 0; g < 32; ++g){
        u64 kk = sKT[g*64 + (lane ^ (g & 15))];
        u32 w0 = (u32)kk, w1 = (u32)(kk >> 32);
        float f0 = bfl(w0), f1 = bfh(w0), f2 = bfl(w1), f3 = bfh(w1);
        float4 q0 = *(const float4*)&sQ[dk0*128 + g*4];
        float4 q1 = *(const float4*)&sQ[dk1*128 + g*4];
        a0 = fmaf(f0,q0.x,a0); a0 = fmaf(f1,q0.y,a0); a0 = fmaf(f2,q0.z,a0); a0 = fmaf(f3,q0.w,a0);
        a1 = fmaf(f0,q1.x,a1); a1 = fmaf(f1,q1.y,a1); a1 = fmaf(f2,q1.z,a1); a1 = fmaf(f3,q1.w,a1);
      }
      sDots[dk0*64 + lane] = a0;
      sDots[dk1*64 + lane] = a1;
    }
    __syncthreads();
    if (t < 64){
      float dv[8], ev[8];
      #pragma unroll
      for (int j = 0; j < 8; ++j) dv[j] = sDots[j*64 + t];
      float mx = dv[0];
      #pragma unroll
      for (int j = 1; j < 8; ++j) mx = fmaxf(mx, dv[j]);
      float sum = 0.f;
      #pragma unroll
      for (int j = 0; j < 8; ++j){ ev[j] = expf(dv[j] - mx); sum += ev[j]; }
      float inv = 1.f/sum;
      #pragma unroll
      for (int j = 0; j < 8; ++j){
        float aa = ev[j]*inv;
        sAttn[j*64 + t] = aa;
        rsacc[j] += aa;
        if (write_attn) attn_out[(size_t)(b*8 + j)*4096 + n0 + t] = aa;
      }
    }
    __syncthreads();
    // updates: thread (k8, q32*4)
    #pragma unroll 8
    for (int n = 0; n < 64; ++n){
      float a = sAttn[k8*64 + n];
      u64 vv = *(const u64*)&sV[n*136 + q32*4];
      u32 w0 = (u32)vv, w1 = (u32)(vv >> 32);
      ua0 = fmaf(a, bfl(w0), ua0);
      ua1 = fmaf(a, bfh(w0), ua1);
      ua2 = fmaf(a, bfl(w1), ua2);
      ua3 = fmaf(a, bfh(w1), ua3);
    }
    __syncthreads();
  }
  float* pb = part + (size_t)(b*8 + chunk)*1040;
  *(float4*)&pb[t*4] = make_float4(ua0, ua1, ua2, ua3);
  if (wid == 0){
    #pragma unroll
    for (int j = 0; j < 8; ++j){
      float v = rsacc[j];
      v += __shfl_xor(v,1); v += __shfl_xor(v,2); v += __shfl_xor(v,4);
      v += __shfl_xor(v,8); v += __shfl_xor(v,16); v += __shfl_xor(v,32);
      if (lane == 0) pb[1024 + j] = v;
    }
  }
}

// ---------------- kernel C: one block per slot-row; coalesced transposed-weight streams ----------------
// grid 512 = (b,k); block 384 threads.
__global__ __launch_bounds__(384) void kC(const float* __restrict__ part,
  float* __restrict__ slots, const float2* __restrict__ gruT,
  const float* __restrict__ bih, const float* __restrict__ bhh,
  const float* __restrict__ lng, const float* __restrict__ lnb,
  const float* __restrict__ w1T, const float* __restrict__ b1,
  const float* __restrict__ w2T, const float* __restrict__ b2,
  float* __restrict__ out_slots, int last)
{
  const int t = threadIdx.x;
  const int r = blockIdx.x, b = r >> 3, k = r & 7;
  __shared__ float sU[128], sS[128], sG1[384], sG2[384];
  __shared__ float sNew[128], sH[128], sH1[256];
  __shared__ float sP[4];

  // phase 0: reduce partial updates -> U; load S
  if (t < 128){
    float rs = 1e-8f;
    #pragma unroll
    for (int c = 0; c < 8; ++c) rs += part[(size_t)(b*8 + c)*1040 + 1024 + k];
    float u = 0.f;
    #pragma unroll
    for (int c = 0; c < 8; ++c) u += part[(size_t)(b*8 + c)*1040 + k*128 + t];
    sU[t] = u / rs;
    sS[t] = slots[r*128 + t];
  }
  __syncthreads();

  // phase 1: GRU gate dots (thread g owns gate g)
  {
    float acc1 = bih[t], acc2 = bhh[t];
    #pragma unroll 8
    for (int d = 0; d < 128; ++d){
      float2 w = gruT[d*384 + t];
      float ud = sU[d], sd = sS[d];
      acc1 = fmaf(ud, w.x, acc1);
      acc2 = fmaf(sd, w.y, acc2);
    }
    sG1[t] = acc1; sG2[t] = acc2;
  }
  __syncthreads();

  // phase 2: combine gates -> new slots (pre-MLP); LN stats
  if (t < 128){
    float rr = 1.f/(1.f + expf(-(sG1[t] + sG2[t])));
    float zz = 1.f/(1.f + expf(-(sG1[128 + t] + sG2[128 + t])));
    float nn = tanhf(sG1[256 + t] + rr*sG2[256 + t]);
    float sl = (1.f - zz)*nn + zz*sS[t];
    sNew[t] = sl;
    float s = red32(sl) + __shfl_xor(red32(sl), 32); // placeholder, replaced below
  }
  __syncthreads();
  // LN over sNew (threads 0..127, 2 waves -> LDS partials)
  if (t < 128){
    float v = sNew[t];
    float s = v, ss = v*v;
    s  += __shfl_xor(s,1);  ss += __shfl_xor(ss,1);
    s  += __shfl_xor(s,2);  ss += __shfl_xor(ss,2);
    s  += __shfl_xor(s,4);  ss += __shfl_xor(ss,4);
    s  += __shfl_xor(s,8);  ss += __shfl_xor(ss,8);
    s  += __shfl_xor(s,16); ss += __shfl_xor(ss,16);
    s  += __shfl_xor(s,32); ss += __shfl_xor(ss,32);
    if ((t & 63) == 0){ sP[(t >> 6)*2] = s; sP[(t >> 6)*2 + 1] = ss; }
  }
  __syncthreads();
  if (t < 128){
    float s = sP[0] + sP[2], ss = sP[1] + sP[3];
    float m = s*0.0078125f, var = ss*0.0078125f - m*m;
    float rstd = rsqrtf(var + 1e-5f);
    sH[t] = (sNew[t] - m)*rstd*lng[t] + lnb[t];
  }
  __syncthreads();

  // phase 3: MLP layer 1 + exact GELU (thread h owns neuron h, h<256)
  if (t < 256){
    float acc = b1[t];
    #pragma unroll 8
    for (int d = 0; d < 128; ++d)
      acc = fmaf(sH[d], w1T[d*256 + t], acc);
    sH1[t] = 0.5f*acc*(1.f + erff(acc*0.70710678118654752f));
  }
  __syncthreads();

  // phase 4: MLP layer 2 + residual; write back
  if (t < 128){
    float acc = b2[t];
    #pragma unroll 8
    for (int j = 0; j < 256; ++j)
      acc = fmaf(sH1[j], w2T[j*128 + t], acc);
    float res = sNew[t] + acc;
    slots[r*128 + t] = res;
    if (last) out_slots[r*128 + t] = res;
  }
}

extern "C" void kernel_launch(void* const* d_in, const int* in_sizes, int n_in,
                              void* d_out, int out_size, void* d_ws, size_t ws_size,
                              hipStream_t stream)
{
  const float* inputs   = (const float*)d_in[0];
  const float* noise    = (const float*)d_in[1];
  const float* ln_in_g  = (const float*)d_in[2];
  const float* ln_in_b  = (const float*)d_in[3];
  const float* ln_sl_g  = (const float*)d_in[4];
  const float* ln_sl_b  = (const float*)d_in[5];
  const float* ln_mlp_g = (const float*)d_in[6];
  const float* ln_mlp_b = (const float*)d_in[7];
  const float* slots_mu = (const float*)d_in[8];
  const float* slots_ls = (const float*)d_in[9];
  const float* Wq  = (const float*)d_in[10];
  const float* Wk  = (const float*)d_in[11];
  const float* Wv  = (const float*)d_in[12];
  const float* Wih = (const float*)d_in[13];
  const float* Whh = (const float*)d_in[14];
  const float* bih = (const float*)d_in[15];
  const float* bhh = (const float*)d_in[16];
  const float* W1  = (const float*)d_in[17];
  const float* b1  = (const float*)d_in[18];
  const float* W2  = (const float*)d_in[19];
  const float* b2  = (const float*)d_in[20];
  float* out = (float*)d_out;

  char* ws = (char*)d_ws;
  u16*   kbuf  = (u16*)ws;                       // 67,108,864 B
  u16*   vbuf  = (u16*)(ws + 67108864);          // 67,108,864 B
  float* slots = (float*)(ws + 134217728);       // 262,144 B
  u16*   wg    = (u16*)(ws + 134479872);         // 65,536 B
  float* c1    = (float*)(ws + 134545408);       // 1,024 B
  float* c2    = (float*)(ws + 134546432);       // 1,024 B
  float* part  = (float*)(ws + 134547456);       // 2,129,920 B
  float2* gruT = (float2*)(ws + 136677376);      // 393,216 B
  float* w1T   = (float*)(ws + 137070592);       // 131,072 B
  float* w2T   = (float*)(ws + 137201664);       // 131,072 B  (end 137,332,736)

  kInitSlots<<<64, 256, 0, stream>>>(noise, slots_mu, slots_ls, slots);
  kInitW<<<1, 256, 0, stream>>>(Wk, Wv, ln_in_g, ln_in_b, wg, c1, c2);
  kInitT<<<448, 256, 0, stream>>>(Wih, Whh, W1, W2, gruT, w1T, w2T);
  kA<<<256, 512, 0, stream>>>(inputs, wg, c1, c2, kbuf, vbuf);
  for (int it = 0; it < 3; ++it){
    kB<<<512, 256, 0, stream>>>(slots, kbuf, vbuf, Wq, ln_sl_g, ln_sl_b,
                                part, out + 65536, it == 2);
    kC<<<512, 384, 0, stream>>>(part, slots, gruT, bih, bhh,
                                ln_mlp_g, ln_mlp_b, w1T, b1, w2T, b2, out, it == 2);
  }
}